// Round 11
// baseline (366.290 us; speedup 1.0000x reference)
//
#include <hip/hip_runtime.h>

typedef unsigned short u16;
typedef unsigned int   u32;
typedef __attribute__((ext_vector_type(8))) short bf16x8;   // 8 bf16 in 4 VGPRs
typedef __attribute__((ext_vector_type(4))) float f32x4;

#define S_LEN 2048
#define EMB   1024
#define NH    16
#define HD    64
#define FF_DIM 4096
#define NROWS 4096   // B*S

__device__ __forceinline__ float b2f(u16 u){ union{u32 i; float f;} c; c.i = ((u32)u)<<16; return c.f; }
// round-half-up bf16 pack: 2 VALU ops (vs 5 for RNE); differs from RNE only on exact ties
__device__ __forceinline__ u16 f2b(float f){ union{float f; u32 u;} c; c.f=f; return (u16)((c.u + 0x8000u)>>16); }
// fast erf-based gelu: A&S 7.1.26 poly, |eps_erf| ~1.5e-7 (invisible after bf16 round)
__device__ __forceinline__ float gelu_f(float x){
    float z  = x * 0.70710678118f;
    float az = fabsf(z);
    float t  = 1.0f / (1.0f + 0.3275911f * az);
    float p  = ((((1.061405429f*t - 1.453152027f)*t + 1.421413741f)*t - 0.284496736f)*t + 0.254829592f)*t;
    float e  = __expf(-az*az);
    float erfv = 1.0f - p*e;
    erfv = (z < 0.f) ? -erfv : erfv;
    return 0.5f*x*(1.0f + erfv);
}

// async global->LDS, 16B per lane; lds dest = wave-uniform base + lane*16 (m97/m104)
__device__ __forceinline__ void load_lds16(const u16* g, u16* l) {
    __builtin_amdgcn_global_load_lds((const __attribute__((address_space(1))) u32*)g,
                                     (__attribute__((address_space(3))) u32*)l, 16, 0, 0);
}

// ---------------------------------------------------------------- LayerNorm (ln1 only; ln2 fused into red_wo_ln2)
template<int XF32>
__global__ __launch_bounds__(256)
void ln_kernel(const void* __restrict__ Xv, const float* __restrict__ G,
               const float* __restrict__ Bv, u16* __restrict__ Y)
{
    const int row = blockIdx.x, t = threadIdx.x;
    float v0, v1, v2, v3;
    if constexpr (XF32) {
        float4 r4 = ((const float4*)((const float*)Xv + (size_t)row*EMB))[t];
        v0 = r4.x; v1 = r4.y; v2 = r4.z; v3 = r4.w;
    } else {
        const u16* xr = (const u16*)Xv + (size_t)row*EMB;
        uint2 raw = *(const uint2*)(xr + t*4);
        v0 = b2f(raw.x & 0xffff); v1 = b2f(raw.x >> 16);
        v2 = b2f(raw.y & 0xffff); v3 = b2f(raw.y >> 16);
    }
    float s  = v0+v1+v2+v3;
    float s2 = v0*v0+v1*v1+v2*v2+v3*v3;
    #pragma unroll
    for (int off = 1; off < 64; off <<= 1) {
        s  += __shfl_xor(s,  off, 64);
        s2 += __shfl_xor(s2, off, 64);
    }
    __shared__ float ps[4], ps2[4];
    const int w = t >> 6, lane = t & 63;
    if (lane == 0) { ps[w] = s; ps2[w] = s2; }
    __syncthreads();
    s  = ps[0]+ps[1]+ps[2]+ps[3];
    s2 = ps2[0]+ps2[1]+ps2[2]+ps2[3];
    const float mu   = s * (1.0f/EMB);
    const float rstd = rsqrtf(fmaxf(s2*(1.0f/EMB) - mu*mu, 0.f) + 1e-5f);
    float4 g4 = ((const float4*)G)[t];
    float4 c4 = ((const float4*)Bv)[t];
    u32 lo = (u32)f2b((v0-mu)*rstd*g4.x + c4.x) | ((u32)f2b((v1-mu)*rstd*g4.y + c4.y) << 16);
    u32 hi = (u32)f2b((v2-mu)*rstd*g4.z + c4.z) | ((u32)f2b((v3-mu)*rstd*g4.w + c4.w) << 16);
    uint2 o; o.x = lo; o.y = hi;
    *(uint2*)(Y + (size_t)row*EMB + t*4) = o;
}

// ---------------------------------------------------------------- transpose+downconvert (f32 [K][N] -> bf16 [N][K])
__global__ __launch_bounds__(256)
void transpose_k(const float* __restrict__ in, u16* __restrict__ out, int K, int N)
{
    __shared__ __align__(16) u16 T[64*72];
    const int k0 = blockIdx.y*64, n0 = blockIdx.x*64, t = threadIdx.x;
    #pragma unroll
    for (int c = 0; c < 4; ++c) {
        int e = t*4 + c*1024, ki = e >> 6, nj = e & 63;
        float4 f = *(const float4*)(in + (size_t)(k0+ki)*N + n0 + nj);
        ushort4 s4; s4.x = f2b(f.x); s4.y = f2b(f.y); s4.z = f2b(f.z); s4.w = f2b(f.w);
        *(ushort4*)&T[ki*72 + nj] = s4;
    }
    __syncthreads();
    #pragma unroll
    for (int c = 0; c < 2; ++c) {
        int e = t*8 + c*2048, ni = e >> 6, kj = e & 63;
        uint4 v; u16* pv = (u16*)&v;
        #pragma unroll
        for (int j = 0; j < 8; ++j) pv[j] = T[(kj+j)*72 + ni];
        *(uint4*)(out + (size_t)(n0+ni)*K + k0 + kj) = v;
    }
}

// ---------------------------------------------------------------- batched weight transpose: wq,wk,wv,wo,w1[,w2] in ONE launch
// id<1024: square weight (id>>8). 1024..2047: w1 (1024x4096 -> [4096][1024]).
// id>=2048 (only when launched with 3072 blocks): w2 (4096x1024 -> [1024][4096]) into w2T.
__global__ __launch_bounds__(256)
void transpose5(const float* __restrict__ wq, const float* __restrict__ wk,
                const float* __restrict__ wv, const float* __restrict__ wo,
                const float* __restrict__ w1, const float* __restrict__ w2,
                u16* __restrict__ out0, u16* __restrict__ w2T)
{
    __shared__ __align__(16) u16 T[64*72];
    const int id = blockIdx.x, t = threadIdx.x;
    const float* in; u16* out; int K, N, n0, k0;
    if (id < 1024) {
        const int w = id >> 8, bid = id & 255;
        in  = (w==0) ? wq : (w==1) ? wk : (w==2) ? wv : wo;
        out = out0 + (size_t)w*(1u<<20);
        K = 1024; N = 1024;
        n0 = (bid & 15)*64; k0 = (bid >> 4)*64;
    } else if (id < 2048) {
        const int bid = id - 1024;
        in = w1; out = out0 + (size_t)4*(1u<<20);
        K = 1024; N = 4096;
        n0 = (bid & 63)*64; k0 = (bid >> 6)*64;
    } else {
        const int bid = id - 2048;          // w2: [4096][1024] f32 -> [1024][4096] bf16
        in = w2; out = w2T;
        K = 4096; N = 1024;
        n0 = (bid & 15)*64; k0 = (bid >> 4)*64;
    }
    #pragma unroll
    for (int c = 0; c < 4; ++c) {
        int e = t*4 + c*1024, ki = e >> 6, nj = e & 63;
        float4 f = *(const float4*)(in + (size_t)(k0+ki)*N + n0 + nj);
        ushort4 s4; s4.x = f2b(f.x); s4.y = f2b(f.y); s4.z = f2b(f.z); s4.w = f2b(f.w);
        *(ushort4*)&T[ki*72 + nj] = s4;
    }
    __syncthreads();
    #pragma unroll
    for (int c = 0; c < 2; ++c) {
        int e = t*8 + c*2048, ni = e >> 6, kj = e & 63;
        uint4 v; u16* pv = (u16*)&v;
        #pragma unroll
        for (int j = 0; j < 8; ++j) pv[j] = T[(kj+j)*72 + ni];
        *(uint4*)(out + (size_t)(n0+ni)*K + k0 + kj) = v;
    }
}

// ================================================================ 256x256 8-phase GEMM  (r6 form, FROZEN)
// T2+T3+T4+T5 (m194-m201 template, plain HIP): 512 thr = 8 waves (2M x 4N), BK=64,
// LDS 128 KiB = 2 buf x {A,B} x 2 k-halves x [256 rows][32 k] bf16.
// Bank swizzle (T2): involution off ^= (off>>3)&0x18, BOTH sides (rule 21).
// Read-once quadrants (k-half x MF-half): 24 ds_read/K-tile (minimum).
// vmcnt discipline: ONE vmcnt(4) per K-tile at its LAST phase.
// r5/r6/r7 schedule variants were REAL-NEUTRAL (wall flat); profiled 2x swings were
// replay artifacts (r9/r10 re-profiles of r6-form = 51us/27% consistently). FROZEN.
__device__ __forceinline__ void stage2(const u16* s0, const u16* s1, int koff, u16* dst, int wave){
    load_lds16(s0 + koff, dst + wave*512);
    load_lds16(s1 + koff, dst + 4096 + wave*512);
}

template<int CBUF, int KS, int MFH, int TAILVM>
__device__ __forceinline__ void phase256(u16* Ls, f32x4 (&acc)[8][4], bf16x8 (&bf)[4],
    int wm, int wn, int lr, int quad, int wave,
    const u16* s0, const u16* s1, int koff, u16* dst)
{
    const u16* ak = Ls + CBUF*32768 + KS*8192;
    const u16* bk = Ls + CBUF*32768 + 16384 + KS*8192;
    bf16x8 af[4];
    #pragma unroll
    for (int i = 0; i < 4; ++i) {
        int off = (wm*128 + (MFH*4 + i)*16 + lr)*32 + quad*8;
        af[i] = *(const bf16x8*)(ak + (off ^ ((off>>3)&0x18)));
    }
    if constexpr (MFH == 0) {
        #pragma unroll
        for (int nf = 0; nf < 4; ++nf) {
            int off = (wn*64 + nf*16 + lr)*32 + quad*8;
            bf[nf] = *(const bf16x8*)(bk + (off ^ ((off>>3)&0x18)));
        }
    }
    stage2(s0, s1, koff, dst, wave);
    __builtin_amdgcn_s_barrier();
    asm volatile("s_waitcnt lgkmcnt(0)" ::: "memory");
    __builtin_amdgcn_s_setprio(1);
    #pragma unroll
    for (int i = 0; i < 4; ++i)
        #pragma unroll
        for (int nf = 0; nf < 4; ++nf)
            acc[MFH*4 + i][nf] = __builtin_amdgcn_mfma_f32_16x16x32_bf16(af[i], bf[nf], acc[MFH*4 + i][nf], 0, 0, 0);
    __builtin_amdgcn_s_setprio(0);
    if constexpr (TAILVM) asm volatile("s_waitcnt vmcnt(4)" ::: "memory");
    __builtin_amdgcn_s_barrier();
}

// shared main loop: runs the 8-phase pipeline over NT K-tiles starting at srcA/B (already K-offset)
__device__ __forceinline__ void gemm256_main(u16* Ls, f32x4 (&acc)[8][4],
    int wm, int wn, int lr, int quad, int wave, int NT,
    const u16* srcA0, const u16* srcA1, const u16* srcB0, const u16* srcB1)
{
    u16* A00 = Ls + 0;
    u16* A01 = Ls + 8192;
    u16* B00 = Ls + 16384;
    u16* B01 = Ls + 16384 + 8192;
    u16* A10 = Ls + 32768;
    u16* A11 = Ls + 32768 + 8192;
    u16* B10 = Ls + 32768 + 16384;
    u16* B11 = Ls + 32768 + 16384 + 8192;

    // prologue: tile0 {Akh0,Bkh0,Akh1,Bkh1}, tile1 {Akh0,Bkh0} = 12 loads (2/stage)
    stage2(srcA0, srcA1, 0,   A00, wave);
    stage2(srcB0, srcB1, 0,   B00, wave);
    stage2(srcA0, srcA1, 32,  A01, wave);
    stage2(srcB0, srcB1, 32,  B01, wave);
    stage2(srcA0, srcA1, 64,  A10, wave);
    stage2(srcB0, srcB1, 64,  B10, wave);
    asm volatile("s_waitcnt vmcnt(4)" ::: "memory");   // tile0 fully resident
    __builtin_amdgcn_s_barrier();

    bf16x8 bf[4];
    for (int U = 0; U < NT; U += 2) {
        const int k1 = ((U+1) & (NT-1))*64;
        const int k2 = ((U+2) & (NT-1))*64;   // wraps at tail: redundant-but-safe reload
        const int k3 = ((U+3) & (NT-1))*64;
        // tile U (buf0): stage targets free'd >=1 barrier earlier (per-slot WAR audit r6)
        phase256<0,0,0,0>(Ls, acc, bf, wm, wn, lr, quad, wave, srcA0, srcA1, k1+32, A11);
        phase256<0,0,1,0>(Ls, acc, bf, wm, wn, lr, quad, wave, srcB0, srcB1, k1+32, B11);
        phase256<0,1,0,0>(Ls, acc, bf, wm, wn, lr, quad, wave, srcA0, srcA1, k2,    A00);
        phase256<0,1,1,1>(Ls, acc, bf, wm, wn, lr, quad, wave, srcB0, srcB1, k2,    B00);
        // tile U+1 (buf1)
        phase256<1,0,0,0>(Ls, acc, bf, wm, wn, lr, quad, wave, srcA0, srcA1, k2+32, A01);
        phase256<1,0,1,0>(Ls, acc, bf, wm, wn, lr, quad, wave, srcB0, srcB1, k2+32, B01);
        phase256<1,1,0,0>(Ls, acc, bf, wm, wn, lr, quad, wave, srcA0, srcA1, k3,    A10);
        phase256<1,1,1,1>(Ls, acc, bf, wm, wn, lr, quad, wave, srcB0, srcB1, k3,    B10);
    }

    // drain ALL DMAs (incl. wrapped tail stages) before repurposing LDS
    asm volatile("s_waitcnt vmcnt(0)" ::: "memory");
    __syncthreads();
}

// MODE 2: gelu -> bf16 C.
// MODE 5: fused QKV. Q,K head-split scatter (C=Q, C2=K); V (n0>=2048) is written
//   TRANSPOSED into C3 = vT [B,H,D,S] directly from the LDS tile (r11: replaces the
//   separate vtrans kernel; column-wise LDS reads, coalesced 16B row stores).
template<int MODE>
__global__ __launch_bounds__(512, 2)
void gemm256(const u16* __restrict__ A, const u16* __restrict__ Bt,
             const float* __restrict__ bias, const float* __restrict__ bias2,
             const float* __restrict__ bias3,
             void* __restrict__ C, void* __restrict__ C2, void* __restrict__ C3,
             int M, int N, int K)
{
    (void)M;
    __shared__ __align__(16) u16 Ls[65536];     // 128 KiB
    const int t = threadIdx.x;
    const int wave = t >> 6, lane = t & 63;
    const int wm = wave >> 2, wn = wave & 3;    // 2 x 4 wave grid
    const int lr = lane & 15, quad = lane >> 4;
    const int n0 = blockIdx.x*256, m0 = blockIdx.y*256;

    // per-lane pre-swizzled global sources: phys chunk c (16B) <- logical chunk c^((c>>3)&3)
    const int c0 = wave*64 + lane, c1 = 512 + wave*64 + lane;
    const int l0 = c0 ^ ((c0 >> 3) & 3), l1 = c1 ^ ((c1 >> 3) & 3);
    const int r0 = l0 >> 2, g0 = l0 & 3;
    const int r1 = l1 >> 2, g1 = l1 & 3;
    const u16* srcA0 = A  + (size_t)(m0 + r0)*K + g0*8;
    const u16* srcA1 = A  + (size_t)(m0 + r1)*K + g1*8;
    const u16* srcB0 = Bt + (size_t)(n0 + r0)*K + g0*8;
    const u16* srcB1 = Bt + (size_t)(n0 + r1)*K + g1*8;

    f32x4 acc[8][4];
    const f32x4 fzero = {0.f, 0.f, 0.f, 0.f};
    #pragma unroll
    for (int i = 0; i < 8; ++i)
        #pragma unroll
        for (int j = 0; j < 4; ++j) acc[i][j] = fzero;

    gemm256_main(Ls, acc, wm, wn, lr, quad, wave, K >> 6, srcA0, srcA1, srcB0, srcB1);

    // ---------------- epilogue: bias(+gelu), stage [256][256] bf16 in LDS, coalesced stores
    float bv[4];
    #pragma unroll
    for (int nf = 0; nf < 4; ++nf) {
        const int col = n0 + wn*64 + nf*16 + lr;
        if constexpr (MODE == 5) {
            const int seg = n0 >> 10;    // 256 | 1024: no straddle
            bv[nf] = (seg == 0 ? bias : (seg == 1 ? bias2 : bias3))[col & 1023];
        } else {
            bv[nf] = bias[col];
        }
    }
    #pragma unroll
    for (int mf = 0; mf < 8; ++mf)
        #pragma unroll
        for (int nf = 0; nf < 4; ++nf)
            #pragma unroll
            for (int r = 0; r < 4; ++r) {
                float v = acc[mf][nf][r] + bv[nf];
                if constexpr (MODE == 2) v = gelu_f(v);
                Ls[(wm*128 + mf*16 + quad*4 + r)*256 + wn*64 + nf*16 + lr] = f2b(v);
            }
    __syncthreads();
    if (MODE == 5 && n0 >= 2048) {
        // V segment: write transposed [B,H,D,S]. Column-wise LDS reads (8x u16 down the
        // s-dim), 16B coalesced stores along S. s0..s0+7 within one batch (s0 mult of 8).
        #pragma unroll
        for (int j = 0; j < 16; ++j) {
            const int idx = j*512 + t;
            const int colL = idx >> 5;          // 0..255
            const int s0L  = (idx & 31)*8;      // row chunk within tile
            u16 col8[8];
            #pragma unroll
            for (int k = 0; k < 8; ++k) col8[k] = Ls[(s0L + k)*256 + colL];
            const int cs = (n0 + colL) & 1023;
            const int h = cs >> 6, d = cs & 63;
            const int row0 = m0 + s0L;
            const int b_ = row0 >> 11, s = row0 & 2047;
            *(uint4*)((u16*)C3 + ((((size_t)(b_*NH + h))*HD + d)*S_LEN) + s) = *(const uint4*)col8;
        }
        return;
    }
    // 256x256 u16 = 8192 16B-chunks; 512 threads x 16 iters
    #pragma unroll
    for (int j = 0; j < 16; ++j) {
        const int idx = j*512 + t;
        const int rr = idx >> 5, ck = idx & 31;
        const u16* src = Ls + rr*256 + ck*8;
        const int row = m0 + rr, col = n0 + ck*8;
        if constexpr (MODE == 5) {
            u16* dstb = (u16*)((n0 >> 10) == 0 ? C : C2);
            const int cs = col & 1023;
            const int h = cs >> 6, d = cs & 63;
            const int b_ = row >> 11, s = row & 2047;
            *(uint4*)(dstb + ((((size_t)(b_*NH + h))*S_LEN + s) << 6) + d) = *(const uint4*)src;
        } else {
            *(uint4*)((u16*)C + (size_t)row*N + col) = *(const uint4*)src;
        }
    }
}

// ================================================================ split-K=4 variant
// grid (N/256, M/256, 4): z = K-split. Writes RAW bf16 partial (no bias) to slab
// (z<2 ? Cl : Ch) + (z&1)*M*N. Fills all 256 CUs for narrow-N deep-K GEMMs (wo, FF2).
__global__ __launch_bounds__(512, 2)
void gemm256sk(const u16* __restrict__ A, const u16* __restrict__ Bt,
               u16* __restrict__ Cl, u16* __restrict__ Ch, int N, int K)
{
    __shared__ __align__(16) u16 Ls[65536];
    const int t = threadIdx.x;
    const int wave = t >> 6, lane = t & 63;
    const int wm = wave >> 2, wn = wave & 3;
    const int lr = lane & 15, quad = lane >> 4;
    const int n0 = blockIdx.x*256, m0 = blockIdx.y*256;
    const int z  = blockIdx.z;
    const int Ks = K >> 2;                       // K-slice per split

    const int c0 = wave*64 + lane, c1 = 512 + wave*64 + lane;
    const int l0 = c0 ^ ((c0 >> 3) & 3), l1 = c1 ^ ((c1 >> 3) & 3);
    const int r0 = l0 >> 2, g0 = l0 & 3;
    const int r1 = l1 >> 2, g1 = l1 & 3;
    const u16* srcA0 = A  + (size_t)(m0 + r0)*K + g0*8 + z*Ks;
    const u16* srcA1 = A  + (size_t)(m0 + r1)*K + g1*8 + z*Ks;
    const u16* srcB0 = Bt + (size_t)(n0 + r0)*K + g0*8 + z*Ks;
    const u16* srcB1 = Bt + (size_t)(n0 + r1)*K + g1*8 + z*Ks;

    f32x4 acc[8][4];
    const f32x4 fzero = {0.f, 0.f, 0.f, 0.f};
    #pragma unroll
    for (int i = 0; i < 8; ++i)
        #pragma unroll
        for (int j = 0; j < 4; ++j) acc[i][j] = fzero;

    gemm256_main(Ls, acc, wm, wn, lr, quad, wave, Ks >> 6, srcA0, srcA1, srcB0, srcB1);

    // epilogue: raw bf16 partial, linear [M][N]
    #pragma unroll
    for (int mf = 0; mf < 8; ++mf)
        #pragma unroll
        for (int nf = 0; nf < 4; ++nf)
            #pragma unroll
            for (int r = 0; r < 4; ++r)
                Ls[(wm*128 + mf*16 + quad*4 + r)*256 + wn*64 + nf*16 + lr] = f2b(acc[mf][nf][r]);
    __syncthreads();
    u16* dst = (z < 2 ? Cl : Ch) + (size_t)(z & 1)*(1u<<22);   // slab stride M*N = 2^22
    #pragma unroll
    for (int j = 0; j < 16; ++j) {
        const int idx = j*512 + t;
        const int rr = idx >> 5, ck = idx & 31;
        *(uint4*)(dst + (size_t)(m0 + rr)*N + n0 + ck*8) = *(const uint4*)(Ls + rr*256 + ck*8);
    }
}

// ---------------------------------------------------------------- fused wo-reduce + LN2
// Per row: y = p0+p1+p2+p3 + bias + x_res(f32); write x1=bf16(y); LN(y) -> h0.
// Writes are same-thread same-element over dead slabs -> race-free. LN uses unrounded f32 y.
__global__ __launch_bounds__(256)
void red_wo_ln2(const u16* __restrict__ pl, const u16* __restrict__ ph,
                const float* __restrict__ xres, const float* __restrict__ bias,
                const float* __restrict__ G, const float* __restrict__ Bv,
                u16* __restrict__ x1, u16* __restrict__ h0)
{
    const int row = blockIdx.x, t = threadIdx.x;
    const int i0 = row*EMB + t*4;
    uint2 a0 = *(const uint2*)(pl + i0);
    uint2 a1 = *(const uint2*)(pl + (1u<<22) + i0);
    uint2 a2 = *(const uint2*)(ph + i0);
    uint2 a3 = *(const uint2*)(ph + (1u<<22) + i0);
    float4 bb = *(const float4*)(bias + t*4);
    float4 xx = *(const float4*)(xres + i0);
    const u16 *q0=(const u16*)&a0, *q1=(const u16*)&a1, *q2=(const u16*)&a2, *q3=(const u16*)&a3;
    const float* bp = (const float*)&bb;
    const float* xp = (const float*)&xx;
    float y[4];
    #pragma unroll
    for (int j = 0; j < 4; ++j)
        y[j] = b2f(q0[j]) + b2f(q1[j]) + b2f(q2[j]) + b2f(q3[j]) + bp[j] + xp[j];
    u16 o16[4];
    #pragma unroll
    for (int j = 0; j < 4; ++j) o16[j] = f2b(y[j]);
    *(uint2*)(x1 + i0) = *(const uint2*)o16;

    float s  = y[0]+y[1]+y[2]+y[3];
    float s2 = y[0]*y[0]+y[1]*y[1]+y[2]*y[2]+y[3]*y[3];
    #pragma unroll
    for (int off = 1; off < 64; off <<= 1) {
        s  += __shfl_xor(s,  off, 64);
        s2 += __shfl_xor(s2, off, 64);
    }
    __shared__ float ps[4], ps2[4];
    const int w = t >> 6, lane = t & 63;
    if (lane == 0) { ps[w] = s; ps2[w] = s2; }
    __syncthreads();
    s  = ps[0]+ps[1]+ps[2]+ps[3];
    s2 = ps2[0]+ps2[1]+ps2[2]+ps2[3];
    const float mu   = s * (1.0f/EMB);
    const float rstd = rsqrtf(fmaxf(s2*(1.0f/EMB) - mu*mu, 0.f) + 1e-5f);
    float4 g4 = *(const float4*)(G + t*4);
    float4 c4 = *(const float4*)(Bv + t*4);
    const float* gp = (const float*)&g4;
    const float* cp = (const float*)&c4;
    u16 h16[4];
    #pragma unroll
    for (int j = 0; j < 4; ++j) h16[j] = f2b((y[j]-mu)*rstd*gp[j] + cp[j]);
    *(uint2*)(h0 + i0) = *(const uint2*)h16;
}

// ff2 fused reduce (big-ws path): out_f32 = (p0+p1+p2+p3) + bias[col] + x1_bf16.
// All 4 slabs in virgin/dead ws regions, d_out written fresh -> race-free single pass.
__global__ __launch_bounds__(256)
void reduce_ff2(const u16* __restrict__ pl, const u16* __restrict__ ph,
                const u16* __restrict__ x1b, const float* __restrict__ bias,
                float* __restrict__ out)
{
    const int i0 = (blockIdx.x*256 + threadIdx.x)*8;
    uint4 a0 = *(const uint4*)(pl + i0);
    uint4 a1 = *(const uint4*)(pl + (1u<<22) + i0);
    uint4 a2 = *(const uint4*)(ph + i0);
    uint4 a3 = *(const uint4*)(ph + (1u<<22) + i0);
    uint4 xr = *(const uint4*)(x1b + i0);
    const int col = i0 & 1023;
    float4 b0 = *(const float4*)(bias + col);
    float4 b1 = *(const float4*)(bias + col + 4);
    const u16 *q0=(const u16*)&a0, *q1=(const u16*)&a1, *q2=(const u16*)&a2, *q3=(const u16*)&a3;
    const u16 *xp=(const u16*)&xr;
    const float bb[8] = {b0.x,b0.y,b0.z,b0.w,b1.x,b1.y,b1.z,b1.w};
    float f[8];
    #pragma unroll
    for (int j = 0; j < 8; ++j)
        f[j] = b2f(q0[j]) + b2f(q1[j]) + b2f(q2[j]) + b2f(q3[j]) + b2f(xp[j]) + bb[j];
    float4 o0 = {f[0],f[1],f[2],f[3]}, o1 = {f[4],f[5],f[6],f[7]};
    *(float4*)(out + i0) = o0;
    *(float4*)(out + i0 + 4) = o1;
}

// ---------------------------------------------------------------- small-ws FF2 reduce (two-pass, r5-proven)
// stage 1: s_bf16 = p0+p1+p2+p3, in-place over slab0 (same-thread same-element, race-free)
__global__ __launch_bounds__(256)
void reduce_sum4(u16* __restrict__ pl, const u16* __restrict__ ph)
{
    const int i0 = (blockIdx.x*256 + threadIdx.x)*8;
    uint4 a0 = *(const uint4*)(pl + i0);
    uint4 a1 = *(const uint4*)(pl + (1u<<22) + i0);
    uint4 a2 = *(const uint4*)(ph + i0);
    uint4 a3 = *(const uint4*)(ph + (1u<<22) + i0);
    const u16 *q0=(const u16*)&a0, *q1=(const u16*)&a1, *q2=(const u16*)&a2, *q3=(const u16*)&a3;
    u16 out[8];
    #pragma unroll
    for (int j = 0; j < 8; ++j)
        out[j] = f2b(b2f(q0[j]) + b2f(q1[j]) + b2f(q2[j]) + b2f(q3[j]));
    *(uint4*)(pl + i0) = *(const uint4*)out;
}

// stage 2: out_f32 = s + bias[col] + x1_bf16  (reads ws only, writes d_out fresh)
__global__ __launch_bounds__(256)
void final_ff2(const u16* __restrict__ s, const u16* __restrict__ x1b,
               const float* __restrict__ bias, float* __restrict__ out)
{
    const int i0 = (blockIdx.x*256 + threadIdx.x)*8;
    uint4 a = *(const uint4*)(s + i0);
    uint4 xr = *(const uint4*)(x1b + i0);
    const int col = i0 & 1023;
    float4 b0 = *(const float4*)(bias + col);
    float4 b1 = *(const float4*)(bias + col + 4);
    const u16 *sp=(const u16*)&a, *xp=(const u16*)&xr;
    const float bb[8] = {b0.x,b0.y,b0.z,b0.w,b1.x,b1.y,b1.z,b1.w};
    float f[8];
    #pragma unroll
    for (int j = 0; j < 8; ++j) f[j] = b2f(sp[j]) + b2f(xp[j]) + bb[j];
    float4 o0 = {f[0],f[1],f[2],f[3]}, o1 = {f[4],f[5],f[6],f[7]};
    *(float4*)(out + i0) = o0;
    *(float4*)(out + i0 + 4) = o1;
}

// ---------------------------------------------------------------- attention (causal)
// Grid (bh fastest): XCD-local KV. Block handles pair {pr, 31-pr}; ONE merged K-loop
// stages each K/V tile once via global_load_lds (shared by 4 waves) and feeds up to
// two Q-tiles. LDS layout [k-half][row][32] keeps the m97 64-B-stride fragment reads.
// Q,K: [B*H][S][64]; Vt: [B*H][64][S]; O: [B][S][1024]
__global__ __launch_bounds__(256, 2)
void attn_kernel(const u16* __restrict__ Q, const u16* __restrict__ Kg,
                 const u16* __restrict__ Vt, u16* __restrict__ O)
{
    const int bh = blockIdx.x;            // fastest -> XCD = bh % 8
    const int pr = blockIdx.y;            // 0..15
    const int qta = pr, qtb = 31 - pr;
    const int t = threadIdx.x, wave = t >> 6, lane = t & 63;
    const int lr = lane & 15, quad = lane >> 4;

    __shared__ __align__(16) u16 Ks[4096];        // [2][64][32]
    __shared__ __align__(16) u16 Vs[4096];        // [2][64][32]
    __shared__ __align__(16) u16 Ps[4][16*72];    // wave-private P round-trip

    const size_t qkbase = (size_t)bh * (S_LEN*HD);
    const int b = bh >> 4, h = bh & 15;
    u16* Pw = Ps[wave];
    const f32x4 fzero = {0.f, 0.f, 0.f, 0.f};

    const u16* qpa = Q + qkbase + (size_t)(qta*64 + wave*16 + lr)*HD + quad*8;
    const u16* qpb = Q + qkbase + (size_t)(qtb*64 + wave*16 + lr)*HD + quad*8;
    bf16x8 qa0 = *(const bf16x8*)qpa, qa1 = *(const bf16x8*)(qpa + 32);
    bf16x8 qb0 = *(const bf16x8*)qpb, qb1 = *(const bf16x8*)(qpb + 32);

    f32x4 oa[4], ob[4];
    float la[4], lb[4];
    #pragma unroll
    for (int dt = 0; dt < 4; ++dt) { oa[dt] = fzero; ob[dt] = fzero; }
    #pragma unroll
    for (int r = 0; r < 4; ++r) { la[r] = 0.f; lb[r] = 0.f; }

    const u16* gK = Kg + qkbase + (size_t)(wave*16 + (lane>>2))*HD + (lane&3)*8;
    const u16* gV = Vt + qkbase + (size_t)(wave*16 + (lane>>2))*S_LEN + (lane&3)*8;
    u16* lK = Ks + wave*512;
    u16* lV = Vs + wave*512;

    const int qrow_qa = qta*64 + wave*16 + quad*4;
    const int qrow_qb = qtb*64 + wave*16 + quad*4;

    for (int kb = 0; kb <= qtb; ++kb) {
        __syncthreads();
        load_lds16(gK + (size_t)kb*4096,      lK);
        load_lds16(gK + (size_t)kb*4096 + 32, lK + 2048);
        load_lds16(gV + kb*64,                lV);
        load_lds16(gV + kb*64 + 32,           lV + 2048);
        __syncthreads();

        #pragma unroll
        for (int tile = 0; tile < 2; ++tile) {
            const int qt = tile ? qta : qtb;
            if (tile && kb > qta) break;
            bf16x8 qf0 = tile ? qa0 : qb0;
            bf16x8 qf1 = tile ? qa1 : qb1;
            f32x4* oacc = tile ? oa : ob;
            float* lp   = tile ? la : lb;
            const int qrowq = tile ? qrow_qa : qrow_qb;

            f32x4 sc[4];
            #pragma unroll
            for (int kt2 = 0; kt2 < 4; ++kt2) {
                bf16x8 kf0 = *(const bf16x8*)&Ks[(kt2*16 + lr)*32 + quad*8];
                bf16x8 kf1 = *(const bf16x8*)&Ks[2048 + (kt2*16 + lr)*32 + quad*8];
                sc[kt2] = __builtin_amdgcn_mfma_f32_16x16x32_bf16(qf0, kf0, fzero, 0, 0, 0);
                sc[kt2] = __builtin_amdgcn_mfma_f32_16x16x32_bf16(qf1, kf1, sc[kt2], 0, 0, 0);
            }
            const bool diag = (kb == qt);
            #pragma unroll
            for (int r = 0; r < 4; ++r) {
                #pragma unroll
                for (int kt2 = 0; kt2 < 4; ++kt2) {
                    int kcol = kb*64 + kt2*16 + lr;
                    float p = (!diag || kcol <= qrowq + r) ? __expf(fminf(sc[kt2][r]*0.125f, 30.f)) : 0.f;
                    lp[r] += p;
                    Pw[(quad*4 + r)*72 + kt2*16 + lr] = f2b(p);
                }
            }
            bf16x8 pf0 = *(const bf16x8*)&Pw[lr*72 + quad*8];
            bf16x8 pf1 = *(const bf16x8*)&Pw[lr*72 + 32 + quad*8];
            #pragma unroll
            for (int dt = 0; dt < 4; ++dt) {
                bf16x8 vf0 = *(const bf16x8*)&Vs[(dt*16 + lr)*32 + quad*8];
                bf16x8 vf1 = *(const bf16x8*)&Vs[2048 + (dt*16 + lr)*32 + quad*8];
                oacc[dt] = __builtin_amdgcn_mfma_f32_16x16x32_bf16(pf0, vf0, oacc[dt], 0, 0, 0);
                oacc[dt] = __builtin_amdgcn_mfma_f32_16x16x32_bf16(pf1, vf1, oacc[dt], 0, 0, 0);
            }
        }
    }

    #pragma unroll
    for (int tile = 0; tile < 2; ++tile) {
        const int qt = tile ? qta : qtb;
        f32x4* oacc = tile ? oa : ob;
        float* lp   = tile ? la : lb;
        #pragma unroll
        for (int r = 0; r < 4; ++r) {
            float v = lp[r];
            v += __shfl_xor(v, 1, 64); v += __shfl_xor(v, 2, 64);
            v += __shfl_xor(v, 4, 64); v += __shfl_xor(v, 8, 64);
            lp[r] = 1.0f / fmaxf(v, 1e-20f);
        }
        #pragma unroll
        for (int dt = 0; dt < 4; ++dt)
            #pragma unroll
            for (int r = 0; r < 4; ++r)
                Pw[(quad*4 + r)*64 + dt*16 + lr] = f2b(oacc[dt][r] * lp[r]);

        const int q = lane >> 2, d0 = (lane & 3)*16;
        u16* dst = O + ((size_t)(b*S_LEN + qt*64 + wave*16 + q))*EMB + h*HD + d0;
        *(uint4*)(dst)     = *(uint4*)&Pw[q*64 + d0];
        *(uint4*)(dst + 8) = *(uint4*)&Pw[q*64 + d0 + 8];
    }
}

// ---------------------------------------------------------------- launch
extern "C" void kernel_launch(void* const* d_in, const int* in_sizes, int n_in,
                              void* d_out, int out_size, void* d_ws, size_t ws_size,
                              hipStream_t stream)
{
    (void)in_sizes; (void)n_in; (void)out_size;
    const float* x    = (const float*)d_in[0];
    // d_in[1] = mask: causal tril, handled analytically
    const float* ln1g = (const float*)d_in[2];
    const float* ln1b = (const float*)d_in[3];
    const float* wq = (const float*)d_in[4];  const float* bq = (const float*)d_in[5];
    const float* wk = (const float*)d_in[6];  const float* bk = (const float*)d_in[7];
    const float* wv = (const float*)d_in[8];  const float* bv = (const float*)d_in[9];
    const float* wo = (const float*)d_in[10]; const float* bo = (const float*)d_in[11];
    const float* ln2g = (const float*)d_in[12]; const float* ln2b = (const float*)d_in[13];
    const float* w1 = (const float*)d_in[14]; const float* b1 = (const float*)d_in[15];
    const float* w2 = (const float*)d_in[16]; const float* b2 = (const float*)d_in[17];

    u16* ws = (u16*)d_ws;
    const size_t M1 = 1u << 20;             // 1M u16 elements (2 MB)
    u16* wqkvT = ws + 0*M1;                 // bf16 [3072][1024] = wqT|wkT|wvT contiguous
    u16* woT = ws + 3*M1;
    u16* w1T = ws + 4*M1;                   // bf16 [4096][1024]
    u16* h0  = ws + 8*M1;                   // bf16 ln out (reused for ln2 out)
    u16* qb  = ws + 12*M1;                  // bf16 [B,H,S,D]
    u16* kb  = ws + 16*M1;                  // bf16 [B,H,S,D]
    u16* vT  = ws + 20*M1;                  // bf16 [B,H,D,S] (written directly by QKV epilogue, r11)
    u16* ao  = ws + 24*M1;                  // bf16 attn out [B,S,E]
    u16* x1  = ws + 28*M1;                  // bf16 residual-1 out (28..32)
    u16* fb  = ws + 12*M1;                  // bf16 MLP hidden [4096][4096] = 12..28 M1 (overlays q/k/vT/ao)
    u16* wosl = ws + 8*M1;                  // wo split-K: 4 slabs over dead h0/qb/kb/vT (8..24M1; ao 24..28 is A-input, no overlap)
    u16* ffsl_lo = ws + 4*M1;               // ff2 split-K slabs 0,1 over dead w1T/h0 (4..12M1)

    // ws-size-dependent layout (resolved at graph capture). RACE NOTE (r10): fb spans
    // 12..28 M1 and is FF2's LIVE A-input -> slabs 2,3 may NOT live at 20..28 M1.
    // Safe spots: virgin ws past 32 M1, or d_out + 2-pass.
    const bool haveW2 = ws_size >= (size_t)36*M1*2;   // w2T at 32..36 M1
    const bool haveHi = ws_size >= (size_t)44*M1*2;   // ff2 slabs 2,3 at 36..44 M1
    u16* w2T     = haveW2 ? ws + 32*M1 : ws + 0*M1;   // else reuse wqkvT space after wo-gemm
    u16* ffsl_hi = haveHi ? ws + 36*M1 : (u16*)d_out; // else d_out scratch + 2-pass reduce

    dim3 blk(256);
    // weight transposes in ONE launch: wq,wk,wv,wo -> 0..4M1, w1 -> 4..8M1 [, w2 -> w2T]
    transpose5<<<dim3(haveW2 ? 3072 : 2048), blk, 0, stream>>>(wq, wk, wv, wo, w1, w2, ws, w2T);

    ln_kernel<1><<<NROWS, blk, 0, stream>>>(x, ln1g, ln1b, h0);

    // fused QKV: 256^2 8-phase kernel, grid = (3072/256, 4096/256); V written transposed
    gemm256<5><<<dim3(12,16), dim3(512), 0, stream>>>(h0, wqkvT, bq, bk, bv,
                                                      qb, kb, vT, NROWS, 3072, EMB);

    attn_kernel<<<dim3(32,16), blk, 0, stream>>>(qb, kb, vT, ao);

    // wo projection: split-K=4 gemm256 (256 blocks = 1/CU), partials in dead 8..24M1
    gemm256sk<<<dim3(4,16,4), dim3(512), 0, stream>>>(ao, woT, wosl, wosl + 8*M1, EMB, EMB);

    // fused wo-reduce + LN2: writes x1 (residual) and h0 (ln2 out) in one pass
    red_wo_ln2<<<NROWS, blk, 0, stream>>>(wosl, wosl + 8*M1, x, bo, ln2g, ln2b, x1, h0);

    if (!haveW2)   // small-ws: transpose w2 into freed wqkvT space (dead after wo-gemm)
        transpose_k<<<dim3(16,64), blk, 0, stream>>>(w2, w2T, FF_DIM, EMB);

    // FF1 (gelu): 256^2 8-phase kernel, grid = (4096/256, 4096/256)
    gemm256<2><<<dim3(16,16), dim3(512), 0, stream>>>(h0, w1T, b1, nullptr, nullptr,
                                                      fb, nullptr, nullptr, NROWS, FF_DIM, EMB);

    // FF2: split-K=4; slabs 0,1 in dead ws; slabs 2,3 in virgin ws (big) or d_out (small)
    gemm256sk<<<dim3(4,16,4), dim3(512), 0, stream>>>(fb, w2T, ffsl_lo, ffsl_hi, EMB, FF_DIM);
    if (haveHi) {
        reduce_ff2<<<2048, blk, 0, stream>>>(ffsl_lo, ffsl_hi, x1, b2, (float*)d_out);
    } else {
        reduce_sum4<<<2048, blk, 0, stream>>>(ffsl_lo, (u16*)d_out);   // sum -> slab0 (in-place safe)
        final_ff2<<<2048, blk, 0, stream>>>(ffsl_lo, x1, b2, (float*)d_out);
    }
}

// Round 12
// 350.008 us; speedup vs baseline: 1.0465x; 1.0465x over previous
//
#include <hip/hip_runtime.h>

typedef unsigned short u16;
typedef unsigned int   u32;
typedef __attribute__((ext_vector_type(8))) short bf16x8;   // 8 bf16 in 4 VGPRs
typedef __attribute__((ext_vector_type(4))) float f32x4;

#define S_LEN 2048
#define EMB   1024
#define NH    16
#define HD    64
#define FF_DIM 4096
#define NROWS 4096   // B*S

__device__ __forceinline__ float b2f(u16 u){ union{u32 i; float f;} c; c.i = ((u32)u)<<16; return c.f; }
// round-half-up bf16 pack: 2 VALU ops (vs 5 for RNE); differs from RNE only on exact ties
__device__ __forceinline__ u16 f2b(float f){ union{float f; u32 u;} c; c.f=f; return (u16)((c.u + 0x8000u)>>16); }
// fast erf-based gelu: A&S 7.1.26 poly, |eps_erf| ~1.5e-7 (invisible after bf16 round)
__device__ __forceinline__ float gelu_f(float x){
    float z  = x * 0.70710678118f;
    float az = fabsf(z);
    float t  = 1.0f / (1.0f + 0.3275911f * az);
    float p  = ((((1.061405429f*t - 1.453152027f)*t + 1.421413741f)*t - 0.284496736f)*t + 0.254829592f)*t;
    float e  = __expf(-az*az);
    float erfv = 1.0f - p*e;
    erfv = (z < 0.f) ? -erfv : erfv;
    return 0.5f*x*(1.0f + erfv);
}

// async global->LDS, 16B per lane; lds dest = wave-uniform base + lane*16 (m97/m104)
__device__ __forceinline__ void load_lds16(const u16* g, u16* l) {
    __builtin_amdgcn_global_load_lds((const __attribute__((address_space(1))) u32*)g,
                                     (__attribute__((address_space(3))) u32*)l, 16, 0, 0);
}

// ---------------------------------------------------------------- LayerNorm (ln1 only; ln2 fused into red_wo_ln2)
template<int XF32>
__global__ __launch_bounds__(256)
void ln_kernel(const void* __restrict__ Xv, const float* __restrict__ G,
               const float* __restrict__ Bv, u16* __restrict__ Y)
{
    const int row = blockIdx.x, t = threadIdx.x;
    float v0, v1, v2, v3;
    if constexpr (XF32) {
        float4 r4 = ((const float4*)((const float*)Xv + (size_t)row*EMB))[t];
        v0 = r4.x; v1 = r4.y; v2 = r4.z; v3 = r4.w;
    } else {
        const u16* xr = (const u16*)Xv + (size_t)row*EMB;
        uint2 raw = *(const uint2*)(xr + t*4);
        v0 = b2f(raw.x & 0xffff); v1 = b2f(raw.x >> 16);
        v2 = b2f(raw.y & 0xffff); v3 = b2f(raw.y >> 16);
    }
    float s  = v0+v1+v2+v3;
    float s2 = v0*v0+v1*v1+v2*v2+v3*v3;
    #pragma unroll
    for (int off = 1; off < 64; off <<= 1) {
        s  += __shfl_xor(s,  off, 64);
        s2 += __shfl_xor(s2, off, 64);
    }
    __shared__ float ps[4], ps2[4];
    const int w = t >> 6, lane = t & 63;
    if (lane == 0) { ps[w] = s; ps2[w] = s2; }
    __syncthreads();
    s  = ps[0]+ps[1]+ps[2]+ps[3];
    s2 = ps2[0]+ps2[1]+ps2[2]+ps2[3];
    const float mu   = s * (1.0f/EMB);
    const float rstd = rsqrtf(fmaxf(s2*(1.0f/EMB) - mu*mu, 0.f) + 1e-5f);
    float4 g4 = ((const float4*)G)[t];
    float4 c4 = ((const float4*)Bv)[t];
    u32 lo = (u32)f2b((v0-mu)*rstd*g4.x + c4.x) | ((u32)f2b((v1-mu)*rstd*g4.y + c4.y) << 16);
    u32 hi = (u32)f2b((v2-mu)*rstd*g4.z + c4.z) | ((u32)f2b((v3-mu)*rstd*g4.w + c4.w) << 16);
    uint2 o; o.x = lo; o.y = hi;
    *(uint2*)(Y + (size_t)row*EMB + t*4) = o;
}

// ---------------------------------------------------------------- transpose+downconvert (f32 [K][N] -> bf16 [N][K])
__global__ __launch_bounds__(256)
void transpose_k(const float* __restrict__ in, u16* __restrict__ out, int K, int N)
{
    __shared__ __align__(16) u16 T[64*72];
    const int k0 = blockIdx.y*64, n0 = blockIdx.x*64, t = threadIdx.x;
    #pragma unroll
    for (int c = 0; c < 4; ++c) {
        int e = t*4 + c*1024, ki = e >> 6, nj = e & 63;
        float4 f = *(const float4*)(in + (size_t)(k0+ki)*N + n0 + nj);
        ushort4 s4; s4.x = f2b(f.x); s4.y = f2b(f.y); s4.z = f2b(f.z); s4.w = f2b(f.w);
        *(ushort4*)&T[ki*72 + nj] = s4;
    }
    __syncthreads();
    #pragma unroll
    for (int c = 0; c < 2; ++c) {
        int e = t*8 + c*2048, ni = e >> 6, kj = e & 63;
        uint4 v; u16* pv = (u16*)&v;
        #pragma unroll
        for (int j = 0; j < 8; ++j) pv[j] = T[(kj+j)*72 + ni];
        *(uint4*)(out + (size_t)(n0+ni)*K + k0 + kj) = v;
    }
}

// ---------------------------------------------------------------- batched weight transpose: wq,wk,wv,wo,w1[,w2] in ONE launch
// id<1024: square weight (id>>8). 1024..2047: w1 (1024x4096 -> [4096][1024]).
// id>=2048 (only when launched with 3072 blocks): w2 (4096x1024 -> [1024][4096]) into w2T.
__global__ __launch_bounds__(256)
void transpose5(const float* __restrict__ wq, const float* __restrict__ wk,
                const float* __restrict__ wv, const float* __restrict__ wo,
                const float* __restrict__ w1, const float* __restrict__ w2,
                u16* __restrict__ out0, u16* __restrict__ w2T)
{
    __shared__ __align__(16) u16 T[64*72];
    const int id = blockIdx.x, t = threadIdx.x;
    const float* in; u16* out; int K, N, n0, k0;
    if (id < 1024) {
        const int w = id >> 8, bid = id & 255;
        in  = (w==0) ? wq : (w==1) ? wk : (w==2) ? wv : wo;
        out = out0 + (size_t)w*(1u<<20);
        K = 1024; N = 1024;
        n0 = (bid & 15)*64; k0 = (bid >> 4)*64;
    } else if (id < 2048) {
        const int bid = id - 1024;
        in = w1; out = out0 + (size_t)4*(1u<<20);
        K = 1024; N = 4096;
        n0 = (bid & 63)*64; k0 = (bid >> 6)*64;
    } else {
        const int bid = id - 2048;          // w2: [4096][1024] f32 -> [1024][4096] bf16
        in = w2; out = w2T;
        K = 4096; N = 1024;
        n0 = (bid & 15)*64; k0 = (bid >> 4)*64;
    }
    #pragma unroll
    for (int c = 0; c < 4; ++c) {
        int e = t*4 + c*1024, ki = e >> 6, nj = e & 63;
        float4 f = *(const float4*)(in + (size_t)(k0+ki)*N + n0 + nj);
        ushort4 s4; s4.x = f2b(f.x); s4.y = f2b(f.y); s4.z = f2b(f.z); s4.w = f2b(f.w);
        *(ushort4*)&T[ki*72 + nj] = s4;
    }
    __syncthreads();
    #pragma unroll
    for (int c = 0; c < 2; ++c) {
        int e = t*8 + c*2048, ni = e >> 6, kj = e & 63;
        uint4 v; u16* pv = (u16*)&v;
        #pragma unroll
        for (int j = 0; j < 8; ++j) pv[j] = T[(kj+j)*72 + ni];
        *(uint4*)(out + (size_t)(n0+ni)*K + k0 + kj) = v;
    }
}

// ---------------------------------------------------------------- bf16 transpose: V [B*H][S][64] -> V^T [B*H][64][S]
// (r12: restored — fusing this into the QKV epilogue caused 32-way LDS bank conflicts, r11 +22us)
__global__ __launch_bounds__(256)
void vtrans(const u16* __restrict__ in, u16* __restrict__ out)
{
    __shared__ __align__(16) u16 T[64*72];
    const int bh = blockIdx.y, s0 = blockIdx.x*64, t = threadIdx.x;
    const size_t base = (size_t)bh * (S_LEN*HD);
    #pragma unroll
    for (int c = 0; c < 2; ++c) {
        int e = t*8 + c*2048, r = e >> 6, d = e & 63;
        *(uint4*)&T[r*72 + d] = *(const uint4*)(in + base + (size_t)(s0 + r)*HD + d);
    }
    __syncthreads();
    #pragma unroll
    for (int c = 0; c < 2; ++c) {
        int e = t*8 + c*2048, d = e >> 6, sj = e & 63;
        uint4 v; u16* pv = (u16*)&v;
        #pragma unroll
        for (int j = 0; j < 8; ++j) pv[j] = T[(sj + j)*72 + d];
        *(uint4*)(out + base + (size_t)d*S_LEN + s0 + sj) = v;
    }
}

// ================================================================ 256x256 8-phase GEMM  (r6 form, FROZEN)
// T2+T3+T4+T5 (m194-m201 template, plain HIP): 512 thr = 8 waves (2M x 4N), BK=64,
// LDS 128 KiB = 2 buf x {A,B} x 2 k-halves x [256 rows][32 k] bf16.
// Bank swizzle (T2): involution off ^= (off>>3)&0x18, BOTH sides (rule 21).
// Read-once quadrants (k-half x MF-half): 24 ds_read/K-tile (minimum).
// vmcnt discipline: ONE vmcnt(4) per K-tile at its LAST phase.
// r5/r6/r7 schedule variants were REAL-NEUTRAL; profiled 2x swings were replay artifacts.
__device__ __forceinline__ void stage2(const u16* s0, const u16* s1, int koff, u16* dst, int wave){
    load_lds16(s0 + koff, dst + wave*512);
    load_lds16(s1 + koff, dst + 4096 + wave*512);
}

template<int CBUF, int KS, int MFH, int TAILVM>
__device__ __forceinline__ void phase256(u16* Ls, f32x4 (&acc)[8][4], bf16x8 (&bf)[4],
    int wm, int wn, int lr, int quad, int wave,
    const u16* s0, const u16* s1, int koff, u16* dst)
{
    const u16* ak = Ls + CBUF*32768 + KS*8192;
    const u16* bk = Ls + CBUF*32768 + 16384 + KS*8192;
    bf16x8 af[4];
    #pragma unroll
    for (int i = 0; i < 4; ++i) {
        int off = (wm*128 + (MFH*4 + i)*16 + lr)*32 + quad*8;
        af[i] = *(const bf16x8*)(ak + (off ^ ((off>>3)&0x18)));
    }
    if constexpr (MFH == 0) {
        #pragma unroll
        for (int nf = 0; nf < 4; ++nf) {
            int off = (wn*64 + nf*16 + lr)*32 + quad*8;
            bf[nf] = *(const bf16x8*)(bk + (off ^ ((off>>3)&0x18)));
        }
    }
    stage2(s0, s1, koff, dst, wave);
    __builtin_amdgcn_s_barrier();
    asm volatile("s_waitcnt lgkmcnt(0)" ::: "memory");
    __builtin_amdgcn_s_setprio(1);
    #pragma unroll
    for (int i = 0; i < 4; ++i)
        #pragma unroll
        for (int nf = 0; nf < 4; ++nf)
            acc[MFH*4 + i][nf] = __builtin_amdgcn_mfma_f32_16x16x32_bf16(af[i], bf[nf], acc[MFH*4 + i][nf], 0, 0, 0);
    __builtin_amdgcn_s_setprio(0);
    if constexpr (TAILVM) asm volatile("s_waitcnt vmcnt(4)" ::: "memory");
    __builtin_amdgcn_s_barrier();
}

// shared main loop: runs the 8-phase pipeline over NT K-tiles starting at srcA/B (already K-offset)
__device__ __forceinline__ void gemm256_main(u16* Ls, f32x4 (&acc)[8][4],
    int wm, int wn, int lr, int quad, int wave, int NT,
    const u16* srcA0, const u16* srcA1, const u16* srcB0, const u16* srcB1)
{
    u16* A00 = Ls + 0;
    u16* A01 = Ls + 8192;
    u16* B00 = Ls + 16384;
    u16* B01 = Ls + 16384 + 8192;
    u16* A10 = Ls + 32768;
    u16* A11 = Ls + 32768 + 8192;
    u16* B10 = Ls + 32768 + 16384;
    u16* B11 = Ls + 32768 + 16384 + 8192;

    // prologue: tile0 {Akh0,Bkh0,Akh1,Bkh1}, tile1 {Akh0,Bkh0} = 12 loads (2/stage)
    stage2(srcA0, srcA1, 0,   A00, wave);
    stage2(srcB0, srcB1, 0,   B00, wave);
    stage2(srcA0, srcA1, 32,  A01, wave);
    stage2(srcB0, srcB1, 32,  B01, wave);
    stage2(srcA0, srcA1, 64,  A10, wave);
    stage2(srcB0, srcB1, 64,  B10, wave);
    asm volatile("s_waitcnt vmcnt(4)" ::: "memory");   // tile0 fully resident
    __builtin_amdgcn_s_barrier();

    bf16x8 bf[4];
    for (int U = 0; U < NT; U += 2) {
        const int k1 = ((U+1) & (NT-1))*64;
        const int k2 = ((U+2) & (NT-1))*64;   // wraps at tail: redundant-but-safe reload
        const int k3 = ((U+3) & (NT-1))*64;
        // tile U (buf0): stage targets free'd >=1 barrier earlier (per-slot WAR audit r6)
        phase256<0,0,0,0>(Ls, acc, bf, wm, wn, lr, quad, wave, srcA0, srcA1, k1+32, A11);
        phase256<0,0,1,0>(Ls, acc, bf, wm, wn, lr, quad, wave, srcB0, srcB1, k1+32, B11);
        phase256<0,1,0,0>(Ls, acc, bf, wm, wn, lr, quad, wave, srcA0, srcA1, k2,    A00);
        phase256<0,1,1,1>(Ls, acc, bf, wm, wn, lr, quad, wave, srcB0, srcB1, k2,    B00);
        // tile U+1 (buf1)
        phase256<1,0,0,0>(Ls, acc, bf, wm, wn, lr, quad, wave, srcA0, srcA1, k2+32, A01);
        phase256<1,0,1,0>(Ls, acc, bf, wm, wn, lr, quad, wave, srcB0, srcB1, k2+32, B01);
        phase256<1,1,0,0>(Ls, acc, bf, wm, wn, lr, quad, wave, srcA0, srcA1, k3,    A10);
        phase256<1,1,1,1>(Ls, acc, bf, wm, wn, lr, quad, wave, srcB0, srcB1, k3,    B10);
    }

    // drain ALL DMAs (incl. wrapped tail stages) before repurposing LDS
    asm volatile("s_waitcnt vmcnt(0)" ::: "memory");
    __syncthreads();
}

// MODE 2: gelu -> bf16 C.   MODE 5: fused QKV head-split scatter (C=Q, C2=K, C3=V).
template<int MODE>
__global__ __launch_bounds__(512, 2)
void gemm256(const u16* __restrict__ A, const u16* __restrict__ Bt,
             const float* __restrict__ bias, const float* __restrict__ bias2,
             const float* __restrict__ bias3,
             void* __restrict__ C, void* __restrict__ C2, void* __restrict__ C3,
             int M, int N, int K)
{
    (void)M;
    __shared__ __align__(16) u16 Ls[65536];     // 128 KiB
    const int t = threadIdx.x;
    const int wave = t >> 6, lane = t & 63;
    const int wm = wave >> 2, wn = wave & 3;    // 2 x 4 wave grid
    const int lr = lane & 15, quad = lane >> 4;
    const int n0 = blockIdx.x*256, m0 = blockIdx.y*256;

    // per-lane pre-swizzled global sources: phys chunk c (16B) <- logical chunk c^((c>>3)&3)
    const int c0 = wave*64 + lane, c1 = 512 + wave*64 + lane;
    const int l0 = c0 ^ ((c0 >> 3) & 3), l1 = c1 ^ ((c1 >> 3) & 3);
    const int r0 = l0 >> 2, g0 = l0 & 3;
    const int r1 = l1 >> 2, g1 = l1 & 3;
    const u16* srcA0 = A  + (size_t)(m0 + r0)*K + g0*8;
    const u16* srcA1 = A  + (size_t)(m0 + r1)*K + g1*8;
    const u16* srcB0 = Bt + (size_t)(n0 + r0)*K + g0*8;
    const u16* srcB1 = Bt + (size_t)(n0 + r1)*K + g1*8;

    f32x4 acc[8][4];
    const f32x4 fzero = {0.f, 0.f, 0.f, 0.f};
    #pragma unroll
    for (int i = 0; i < 8; ++i)
        #pragma unroll
        for (int j = 0; j < 4; ++j) acc[i][j] = fzero;

    gemm256_main(Ls, acc, wm, wn, lr, quad, wave, K >> 6, srcA0, srcA1, srcB0, srcB1);

    // ---------------- epilogue: bias(+gelu), stage [256][256] bf16 in LDS, coalesced stores
    float bv[4];
    #pragma unroll
    for (int nf = 0; nf < 4; ++nf) {
        const int col = n0 + wn*64 + nf*16 + lr;
        if constexpr (MODE == 5) {
            const int seg = n0 >> 10;    // 256 | 1024: no straddle
            bv[nf] = (seg == 0 ? bias : (seg == 1 ? bias2 : bias3))[col & 1023];
        } else {
            bv[nf] = bias[col];
        }
    }
    #pragma unroll
    for (int mf = 0; mf < 8; ++mf)
        #pragma unroll
        for (int nf = 0; nf < 4; ++nf)
            #pragma unroll
            for (int r = 0; r < 4; ++r) {
                float v = acc[mf][nf][r] + bv[nf];
                if constexpr (MODE == 2) v = gelu_f(v);
                Ls[(wm*128 + mf*16 + quad*4 + r)*256 + wn*64 + nf*16 + lr] = f2b(v);
            }
    __syncthreads();
    // 256x256 u16 = 8192 16B-chunks; 512 threads x 16 iters
    #pragma unroll
    for (int j = 0; j < 16; ++j) {
        const int idx = j*512 + t;
        const int rr = idx >> 5, ck = idx & 31;
        const u16* src = Ls + rr*256 + ck*8;
        const int row = m0 + rr, col = n0 + ck*8;
        if constexpr (MODE == 5) {
            const int seg = n0 >> 10;
            u16* dstb = (u16*)(seg == 0 ? C : (seg == 1 ? C2 : C3));
            const int cs = col & 1023;
            const int h = cs >> 6, d = cs & 63;
            const int b_ = row >> 11, s = row & 2047;
            *(uint4*)(dstb + ((((size_t)(b_*NH + h))*S_LEN + s) << 6) + d) = *(const uint4*)src;
        } else {
            *(uint4*)((u16*)C + (size_t)row*N + col) = *(const uint4*)src;
        }
    }
}

// ================================================================ split-K=4 variant
// grid (N/256, M/256, 4): z = K-split. Writes RAW bf16 partial (no bias) to slab
// (z<2 ? Cl : Ch) + (z&1)*M*N. Fills all 256 CUs for narrow-N deep-K GEMMs (wo, FF2).
__global__ __launch_bounds__(512, 2)
void gemm256sk(const u16* __restrict__ A, const u16* __restrict__ Bt,
               u16* __restrict__ Cl, u16* __restrict__ Ch, int N, int K)
{
    __shared__ __align__(16) u16 Ls[65536];
    const int t = threadIdx.x;
    const int wave = t >> 6, lane = t & 63;
    const int wm = wave >> 2, wn = wave & 3;
    const int lr = lane & 15, quad = lane >> 4;
    const int n0 = blockIdx.x*256, m0 = blockIdx.y*256;
    const int z  = blockIdx.z;
    const int Ks = K >> 2;                       // K-slice per split

    const int c0 = wave*64 + lane, c1 = 512 + wave*64 + lane;
    const int l0 = c0 ^ ((c0 >> 3) & 3), l1 = c1 ^ ((c1 >> 3) & 3);
    const int r0 = l0 >> 2, g0 = l0 & 3;
    const int r1 = l1 >> 2, g1 = l1 & 3;
    const u16* srcA0 = A  + (size_t)(m0 + r0)*K + g0*8 + z*Ks;
    const u16* srcA1 = A  + (size_t)(m0 + r1)*K + g1*8 + z*Ks;
    const u16* srcB0 = Bt + (size_t)(n0 + r0)*K + g0*8 + z*Ks;
    const u16* srcB1 = Bt + (size_t)(n0 + r1)*K + g1*8 + z*Ks;

    f32x4 acc[8][4];
    const f32x4 fzero = {0.f, 0.f, 0.f, 0.f};
    #pragma unroll
    for (int i = 0; i < 8; ++i)
        #pragma unroll
        for (int j = 0; j < 4; ++j) acc[i][j] = fzero;

    gemm256_main(Ls, acc, wm, wn, lr, quad, wave, Ks >> 6, srcA0, srcA1, srcB0, srcB1);

    // epilogue: raw bf16 partial, linear [M][N]
    #pragma unroll
    for (int mf = 0; mf < 8; ++mf)
        #pragma unroll
        for (int nf = 0; nf < 4; ++nf)
            #pragma unroll
            for (int r = 0; r < 4; ++r)
                Ls[(wm*128 + mf*16 + quad*4 + r)*256 + wn*64 + nf*16 + lr] = f2b(acc[mf][nf][r]);
    __syncthreads();
    u16* dst = (z < 2 ? Cl : Ch) + (size_t)(z & 1)*(1u<<22);   // slab stride M*N = 2^22
    #pragma unroll
    for (int j = 0; j < 16; ++j) {
        const int idx = j*512 + t;
        const int rr = idx >> 5, ck = idx & 31;
        *(uint4*)(dst + (size_t)(m0 + rr)*N + n0 + ck*8) = *(const uint4*)(Ls + rr*256 + ck*8);
    }
}

// ---------------------------------------------------------------- fused wo-reduce + LN2
// Per row: y = p0+p1+p2+p3 + bias + x_res(f32); write x1=bf16(y); LN(y) -> h0.
// Writes are same-thread same-element over dead slabs -> race-free. LN uses unrounded f32 y.
__global__ __launch_bounds__(256)
void red_wo_ln2(const u16* __restrict__ pl, const u16* __restrict__ ph,
                const float* __restrict__ xres, const float* __restrict__ bias,
                const float* __restrict__ G, const float* __restrict__ Bv,
                u16* __restrict__ x1, u16* __restrict__ h0)
{
    const int row = blockIdx.x, t = threadIdx.x;
    const int i0 = row*EMB + t*4;
    uint2 a0 = *(const uint2*)(pl + i0);
    uint2 a1 = *(const uint2*)(pl + (1u<<22) + i0);
    uint2 a2 = *(const uint2*)(ph + i0);
    uint2 a3 = *(const uint2*)(ph + (1u<<22) + i0);
    float4 bb = *(const float4*)(bias + t*4);
    float4 xx = *(const float4*)(xres + i0);
    const u16 *q0=(const u16*)&a0, *q1=(const u16*)&a1, *q2=(const u16*)&a2, *q3=(const u16*)&a3;
    const float* bp = (const float*)&bb;
    const float* xp = (const float*)&xx;
    float y[4];
    #pragma unroll
    for (int j = 0; j < 4; ++j)
        y[j] = b2f(q0[j]) + b2f(q1[j]) + b2f(q2[j]) + b2f(q3[j]) + bp[j] + xp[j];
    u16 o16[4];
    #pragma unroll
    for (int j = 0; j < 4; ++j) o16[j] = f2b(y[j]);
    *(uint2*)(x1 + i0) = *(const uint2*)o16;

    float s  = y[0]+y[1]+y[2]+y[3];
    float s2 = y[0]*y[0]+y[1]*y[1]+y[2]*y[2]+y[3]*y[3];
    #pragma unroll
    for (int off = 1; off < 64; off <<= 1) {
        s  += __shfl_xor(s,  off, 64);
        s2 += __shfl_xor(s2, off, 64);
    }
    __shared__ float ps[4], ps2[4];
    const int w = t >> 6, lane = t & 63;
    if (lane == 0) { ps[w] = s; ps2[w] = s2; }
    __syncthreads();
    s  = ps[0]+ps[1]+ps[2]+ps[3];
    s2 = ps2[0]+ps2[1]+ps2[2]+ps2[3];
    const float mu   = s * (1.0f/EMB);
    const float rstd = rsqrtf(fmaxf(s2*(1.0f/EMB) - mu*mu, 0.f) + 1e-5f);
    float4 g4 = *(const float4*)(G + t*4);
    float4 c4 = *(const float4*)(Bv + t*4);
    const float* gp = (const float*)&g4;
    const float* cp = (const float*)&c4;
    u16 h16[4];
    #pragma unroll
    for (int j = 0; j < 4; ++j) h16[j] = f2b((y[j]-mu)*rstd*gp[j] + cp[j]);
    *(uint2*)(h0 + i0) = *(const uint2*)h16;
}

// ff2 fused reduce (big-ws path): out_f32 = (p0+p1+p2+p3) + bias[col] + x1_bf16.
// All 4 slabs in virgin/dead ws regions, d_out written fresh -> race-free single pass.
__global__ __launch_bounds__(256)
void reduce_ff2(const u16* __restrict__ pl, const u16* __restrict__ ph,
                const u16* __restrict__ x1b, const float* __restrict__ bias,
                float* __restrict__ out)
{
    const int i0 = (blockIdx.x*256 + threadIdx.x)*8;
    uint4 a0 = *(const uint4*)(pl + i0);
    uint4 a1 = *(const uint4*)(pl + (1u<<22) + i0);
    uint4 a2 = *(const uint4*)(ph + i0);
    uint4 a3 = *(const uint4*)(ph + (1u<<22) + i0);
    uint4 xr = *(const uint4*)(x1b + i0);
    const int col = i0 & 1023;
    float4 b0 = *(const float4*)(bias + col);
    float4 b1 = *(const float4*)(bias + col + 4);
    const u16 *q0=(const u16*)&a0, *q1=(const u16*)&a1, *q2=(const u16*)&a2, *q3=(const u16*)&a3;
    const u16 *xp=(const u16*)&xr;
    const float bb[8] = {b0.x,b0.y,b0.z,b0.w,b1.x,b1.y,b1.z,b1.w};
    float f[8];
    #pragma unroll
    for (int j = 0; j < 8; ++j)
        f[j] = b2f(q0[j]) + b2f(q1[j]) + b2f(q2[j]) + b2f(q3[j]) + b2f(xp[j]) + bb[j];
    float4 o0 = {f[0],f[1],f[2],f[3]}, o1 = {f[4],f[5],f[6],f[7]};
    *(float4*)(out + i0) = o0;
    *(float4*)(out + i0 + 4) = o1;
}

// ---------------------------------------------------------------- small-ws FF2 reduce (two-pass, r5-proven)
// stage 1: s_bf16 = p0+p1+p2+p3, in-place over slab0 (same-thread same-element, race-free)
__global__ __launch_bounds__(256)
void reduce_sum4(u16* __restrict__ pl, const u16* __restrict__ ph)
{
    const int i0 = (blockIdx.x*256 + threadIdx.x)*8;
    uint4 a0 = *(const uint4*)(pl + i0);
    uint4 a1 = *(const uint4*)(pl + (1u<<22) + i0);
    uint4 a2 = *(const uint4*)(ph + i0);
    uint4 a3 = *(const uint4*)(ph + (1u<<22) + i0);
    const u16 *q0=(const u16*)&a0, *q1=(const u16*)&a1, *q2=(const u16*)&a2, *q3=(const u16*)&a3;
    u16 out[8];
    #pragma unroll
    for (int j = 0; j < 8; ++j)
        out[j] = f2b(b2f(q0[j]) + b2f(q1[j]) + b2f(q2[j]) + b2f(q3[j]));
    *(uint4*)(pl + i0) = *(const uint4*)out;
}

// stage 2: out_f32 = s + bias[col] + x1_bf16  (reads ws only, writes d_out fresh)
__global__ __launch_bounds__(256)
void final_ff2(const u16* __restrict__ s, const u16* __restrict__ x1b,
               const float* __restrict__ bias, float* __restrict__ out)
{
    const int i0 = (blockIdx.x*256 + threadIdx.x)*8;
    uint4 a = *(const uint4*)(s + i0);
    uint4 xr = *(const uint4*)(x1b + i0);
    const int col = i0 & 1023;
    float4 b0 = *(const float4*)(bias + col);
    float4 b1 = *(const float4*)(bias + col + 4);
    const u16 *sp=(const u16*)&a, *xp=(const u16*)&xr;
    const float bb[8] = {b0.x,b0.y,b0.z,b0.w,b1.x,b1.y,b1.z,b1.w};
    float f[8];
    #pragma unroll
    for (int j = 0; j < 8; ++j) f[j] = b2f(sp[j]) + b2f(xp[j]) + bb[j];
    float4 o0 = {f[0],f[1],f[2],f[3]}, o1 = {f[4],f[5],f[6],f[7]};
    *(float4*)(out + i0) = o0;
    *(float4*)(out + i0 + 4) = o1;
}

// ---------------------------------------------------------------- attention (causal, r12: K/V double-buffered)
// Grid (bh fastest): XCD-local KV. Block handles pair {pr, 31-pr}; ONE merged K-loop,
// K/V tiles double-buffered (T3 minimum): stage kb+1 via global_load_lds BEFORE computing
// kb, single bottom __syncthreads per kb (vmcnt(0) drain lands after 2-tile compute).
// Proven-correct in r1 bench. Q,K: [B*H][S][64]; Vt: [B*H][64][S]; O: [B][S][1024]
__global__ __launch_bounds__(256, 2)
void attn_kernel(const u16* __restrict__ Q, const u16* __restrict__ Kg,
                 const u16* __restrict__ Vt, u16* __restrict__ O)
{
    const int bh = blockIdx.x;            // fastest -> XCD = bh % 8
    const int pr = blockIdx.y;            // 0..15
    const int qta = pr, qtb = 31 - pr;
    const int t = threadIdx.x, wave = t >> 6, lane = t & 63;
    const int lr = lane & 15, quad = lane >> 4;

    __shared__ __align__(16) u16 Ks[8192];        // [2 buf][2 k-half][64][32]
    __shared__ __align__(16) u16 Vs[8192];        // [2 buf][2 k-half][64][32]
    __shared__ __align__(16) u16 Ps[4][16*72];    // wave-private P round-trip

    const size_t qkbase = (size_t)bh * (S_LEN*HD);
    const int b = bh >> 4, h = bh & 15;
    u16* Pw = Ps[wave];
    const f32x4 fzero = {0.f, 0.f, 0.f, 0.f};

    const u16* qpa = Q + qkbase + (size_t)(qta*64 + wave*16 + lr)*HD + quad*8;
    const u16* qpb = Q + qkbase + (size_t)(qtb*64 + wave*16 + lr)*HD + quad*8;
    bf16x8 qa0 = *(const bf16x8*)qpa, qa1 = *(const bf16x8*)(qpa + 32);
    bf16x8 qb0 = *(const bf16x8*)qpb, qb1 = *(const bf16x8*)(qpb + 32);

    f32x4 oa[4], ob[4];
    float la[4], lb[4];
    #pragma unroll
    for (int dt = 0; dt < 4; ++dt) { oa[dt] = fzero; ob[dt] = fzero; }
    #pragma unroll
    for (int r = 0; r < 4; ++r) { la[r] = 0.f; lb[r] = 0.f; }

    const u16* gK = Kg + qkbase + (size_t)(wave*16 + (lane>>2))*HD + (lane&3)*8;
    const u16* gV = Vt + qkbase + (size_t)(wave*16 + (lane>>2))*S_LEN + (lane&3)*8;

    const int qrow_qa = qta*64 + wave*16 + quad*4;
    const int qrow_qb = qtb*64 + wave*16 + quad*4;

    auto STAGEKV = [&](int kb, int p) {
        load_lds16(gK + (size_t)kb*4096,      Ks + p*4096 + wave*512);
        load_lds16(gK + (size_t)kb*4096 + 32, Ks + p*4096 + wave*512 + 2048);
        load_lds16(gV + kb*64,                Vs + p*4096 + wave*512);
        load_lds16(gV + kb*64 + 32,           Vs + p*4096 + wave*512 + 2048);
    };

    STAGEKV(0, 0);
    __syncthreads();
    for (int kb = 0; kb <= qtb; ++kb) {
        const int p = kb & 1;
        if (kb < qtb) STAGEKV(kb + 1, p ^ 1);   // prefetch next K/V tile

        #pragma unroll
        for (int tile = 0; tile < 2; ++tile) {
            const int qt = tile ? qta : qtb;
            if (tile && kb > qta) break;
            bf16x8 qf0 = tile ? qa0 : qb0;
            bf16x8 qf1 = tile ? qa1 : qb1;
            f32x4* oacc = tile ? oa : ob;
            float* lp   = tile ? la : lb;
            const int qrowq = tile ? qrow_qa : qrow_qb;

            f32x4 sc[4];
            #pragma unroll
            for (int kt2 = 0; kt2 < 4; ++kt2) {
                bf16x8 kf0 = *(const bf16x8*)&Ks[p*4096 + (kt2*16 + lr)*32 + quad*8];
                bf16x8 kf1 = *(const bf16x8*)&Ks[p*4096 + 2048 + (kt2*16 + lr)*32 + quad*8];
                sc[kt2] = __builtin_amdgcn_mfma_f32_16x16x32_bf16(qf0, kf0, fzero, 0, 0, 0);
                sc[kt2] = __builtin_amdgcn_mfma_f32_16x16x32_bf16(qf1, kf1, sc[kt2], 0, 0, 0);
            }
            const bool diag = (kb == qt);
            #pragma unroll
            for (int r = 0; r < 4; ++r) {
                #pragma unroll
                for (int kt2 = 0; kt2 < 4; ++kt2) {
                    int kcol = kb*64 + kt2*16 + lr;
                    float pv = (!diag || kcol <= qrowq + r) ? __expf(fminf(sc[kt2][r]*0.125f, 30.f)) : 0.f;
                    lp[r] += pv;
                    Pw[(quad*4 + r)*72 + kt2*16 + lr] = f2b(pv);
                }
            }
            bf16x8 pf0 = *(const bf16x8*)&Pw[lr*72 + quad*8];
            bf16x8 pf1 = *(const bf16x8*)&Pw[lr*72 + 32 + quad*8];
            #pragma unroll
            for (int dt = 0; dt < 4; ++dt) {
                bf16x8 vf0 = *(const bf16x8*)&Vs[p*4096 + (dt*16 + lr)*32 + quad*8];
                bf16x8 vf1 = *(const bf16x8*)&Vs[p*4096 + 2048 + (dt*16 + lr)*32 + quad*8];
                oacc[dt] = __builtin_amdgcn_mfma_f32_16x16x32_bf16(pf0, vf0, oacc[dt], 0, 0, 0);
                oacc[dt] = __builtin_amdgcn_mfma_f32_16x16x32_bf16(pf1, vf1, oacc[dt], 0, 0, 0);
            }
        }
        __syncthreads();    // drain: kb+1 staged, buf p reads complete
    }

    #pragma unroll
    for (int tile = 0; tile < 2; ++tile) {
        const int qt = tile ? qta : qtb;
        f32x4* oacc = tile ? oa : ob;
        float* lp   = tile ? la : lb;
        #pragma unroll
        for (int r = 0; r < 4; ++r) {
            float v = lp[r];
            v += __shfl_xor(v, 1, 64); v += __shfl_xor(v, 2, 64);
            v += __shfl_xor(v, 4, 64); v += __shfl_xor(v, 8, 64);
            lp[r] = 1.0f / fmaxf(v, 1e-20f);
        }
        #pragma unroll
        for (int dt = 0; dt < 4; ++dt)
            #pragma unroll
            for (int r = 0; r < 4; ++r)
                Pw[(quad*4 + r)*64 + dt*16 + lr] = f2b(oacc[dt][r] * lp[r]);

        const int q = lane >> 2, d0 = (lane & 3)*16;
        u16* dst = O + ((size_t)(b*S_LEN + qt*64 + wave*16 + q))*EMB + h*HD + d0;
        *(uint4*)(dst)     = *(uint4*)&Pw[q*64 + d0];
        *(uint4*)(dst + 8) = *(uint4*)&Pw[q*64 + d0 + 8];
    }
}

// ---------------------------------------------------------------- launch
extern "C" void kernel_launch(void* const* d_in, const int* in_sizes, int n_in,
                              void* d_out, int out_size, void* d_ws, size_t ws_size,
                              hipStream_t stream)
{
    (void)in_sizes; (void)n_in; (void)out_size;
    const float* x    = (const float*)d_in[0];
    // d_in[1] = mask: causal tril, handled analytically
    const float* ln1g = (const float*)d_in[2];
    const float* ln1b = (const float*)d_in[3];
    const float* wq = (const float*)d_in[4];  const float* bq = (const float*)d_in[5];
    const float* wk = (const float*)d_in[6];  const float* bk = (const float*)d_in[7];
    const float* wv = (const float*)d_in[8];  const float* bv = (const float*)d_in[9];
    const float* wo = (const float*)d_in[10]; const float* bo = (const float*)d_in[11];
    const float* ln2g = (const float*)d_in[12]; const float* ln2b = (const float*)d_in[13];
    const float* w1 = (const float*)d_in[14]; const float* b1 = (const float*)d_in[15];
    const float* w2 = (const float*)d_in[16]; const float* b2 = (const float*)d_in[17];

    u16* ws = (u16*)d_ws;
    const size_t M1 = 1u << 20;             // 1M u16 elements (2 MB)
    u16* wqkvT = ws + 0*M1;                 // bf16 [3072][1024] = wqT|wkT|wvT contiguous
    u16* woT = ws + 3*M1;
    u16* w1T = ws + 4*M1;                   // bf16 [4096][1024]
    u16* h0  = ws + 8*M1;                   // bf16 ln out (reused for ln2 out)
    u16* qb  = ws + 12*M1;                  // bf16 [B,H,S,D]
    u16* kb  = ws + 16*M1;                  // bf16 [B,H,S,D]
    u16* vT  = ws + 20*M1;                  // bf16 [B,H,D,S]
    u16* ao  = ws + 24*M1;                  // bf16 attn out [B,S,E]
    u16* vb  = ws + 24*M1;                  // bf16 V [B,H,S,D] (dead before attn writes ao)
    u16* x1  = ws + 28*M1;                  // bf16 residual-1 out (28..32)
    u16* fb  = ws + 12*M1;                  // bf16 MLP hidden [4096][4096] = 12..28 M1
    u16* wosl = ws + 8*M1;                  // wo split-K: 4 slabs over dead h0/qb/kb/vT (8..24M1)
    u16* ffsl_lo = ws + 4*M1;               // ff2 split-K slabs 0,1 over dead w1T/h0 (4..12M1)

    // ws-size-dependent layout (resolved at graph capture). fb spans 12..28 M1 and is
    // FF2's LIVE A-input -> slabs 2,3 may NOT live there. Safe: virgin ws >32M1, or d_out+2-pass.
    const bool haveW2 = ws_size >= (size_t)36*M1*2;   // w2T at 32..36 M1
    const bool haveHi = ws_size >= (size_t)44*M1*2;   // ff2 slabs 2,3 at 36..44 M1
    u16* w2T     = haveW2 ? ws + 32*M1 : ws + 0*M1;   // else reuse wqkvT space after wo-gemm
    u16* ffsl_hi = haveHi ? ws + 36*M1 : (u16*)d_out; // else d_out scratch + 2-pass reduce

    dim3 blk(256);
    // weight transposes in ONE launch: wq,wk,wv,wo -> 0..4M1, w1 -> 4..8M1 [, w2 -> w2T]
    transpose5<<<dim3(haveW2 ? 3072 : 2048), blk, 0, stream>>>(wq, wk, wv, wo, w1, w2, ws, w2T);

    ln_kernel<1><<<NROWS, blk, 0, stream>>>(x, ln1g, ln1b, h0);

    // fused QKV: 256^2 8-phase kernel, grid = (3072/256, 4096/256)
    gemm256<5><<<dim3(12,16), dim3(512), 0, stream>>>(h0, wqkvT, bq, bk, bv,
                                                      qb, kb, vb, NROWS, 3072, EMB);

    vtrans<<<dim3(32,32), blk, 0, stream>>>(vb, vT);

    attn_kernel<<<dim3(32,16), blk, 0, stream>>>(qb, kb, vT, ao);

    // wo projection: split-K=4 gemm256 (256 blocks = 1/CU), partials in dead 8..24M1
    gemm256sk<<<dim3(4,16,4), dim3(512), 0, stream>>>(ao, woT, wosl, wosl + 8*M1, EMB, EMB);

    // fused wo-reduce + LN2: writes x1 (residual) and h0 (ln2 out) in one pass
    red_wo_ln2<<<NROWS, blk, 0, stream>>>(wosl, wosl + 8*M1, x, bo, ln2g, ln2b, x1, h0);

    if (!haveW2)   // small-ws: transpose w2 into freed wqkvT space (dead after wo-gemm)
        transpose_k<<<dim3(16,64), blk, 0, stream>>>(w2, w2T, FF_DIM, EMB);

    // FF1 (gelu): 256^2 8-phase kernel, grid = (4096/256, 4096/256)
    gemm256<2><<<dim3(16,16), dim3(512), 0, stream>>>(h0, w1T, b1, nullptr, nullptr,
                                                      fb, nullptr, nullptr, NROWS, FF_DIM, EMB);

    // FF2: split-K=4; slabs 0,1 in dead ws; slabs 2,3 in virgin ws (big) or d_out (small)
    gemm256sk<<<dim3(4,16,4), dim3(512), 0, stream>>>(fb, w2T, ffsl_lo, ffsl_hi, EMB, FF_DIM);
    if (haveHi) {
        reduce_ff2<<<2048, blk, 0, stream>>>(ffsl_lo, ffsl_hi, x1, b2, (float*)d_out);
    } else {
        reduce_sum4<<<2048, blk, 0, stream>>>(ffsl_lo, (u16*)d_out);   // sum -> slab0 (in-place safe)
        final_ff2<<<2048, blk, 0, stream>>>(ffsl_lo, x1, b2, (float*)d_out);
    }
}